// Round 3
// baseline (241.402 us; speedup 1.0000x reference)
//
#include <hip/hip_runtime.h>

#define K_DIM 4096
#define M_DIM 12288
#define KW (K_DIM / 4)      // packed int32 words per weight row = 1024
#define NT_K (K_DIM / 128)  // 32 K-tiles of 128 elements (=128 bytes int8)
#define BM 256              // token rows per block tile
#define BN 256              // weight rows per block tile
#define GN 16               // 4096/256 token tiles
#define GM 48               // 12288/256 weight tiles

typedef __attribute__((ext_vector_type(4))) int i32x4;
typedef __attribute__((ext_vector_type(4))) unsigned int u32x4;

__device__ __forceinline__ int quant1(float v, float qs) {
  float r = rintf(v * qs);  // round half-to-even, matches jnp.round
  r = fminf(127.f, fmaxf(-128.f, r));
  return (int)r;
}

// unpack one packed byte into 4 code bytes (0..3) at permuted positions
__device__ __forceinline__ unsigned int unp(unsigned int uv) {
  return ((uv >> 6) | (uv << 4) | (uv << 14) | (uv << 24)) & 0x03030303u;
}

// One block per token row: absmax -> int8 quantize (k-permuted pack) + rowsum.
__global__ __launch_bounds__(256) void quant_kernel(const float* __restrict__ x,
                                                    unsigned int* __restrict__ xq,
                                                    float2* __restrict__ scales) {
  const int n = blockIdx.x;
  const int t = threadIdx.x;
  const float* __restrict__ row = x + (size_t)n * K_DIM;
  const float4* __restrict__ row4 = (const float4*)row;

  float am = 0.f;
#pragma unroll
  for (int p = 0; p < 4; ++p) {
    float4 v = row4[t + 256 * p];
    am = fmaxf(am, fmaxf(fmaxf(fabsf(v.x), fabsf(v.y)), fmaxf(fabsf(v.z), fabsf(v.w))));
  }
#pragma unroll
  for (int off = 32; off; off >>= 1) am = fmaxf(am, __shfl_xor(am, off, 64));
  __shared__ float redf[4];
  __shared__ int redi[4];
  const int wave = t >> 6, lane = t & 63;
  if (lane == 0) redf[wave] = am;
  __syncthreads();
  am = fmaxf(fmaxf(redf[0], redf[1]), fmaxf(redf[2], redf[3]));
  const float clipped = fmaxf(am, 1e-5f);
  const float qs = 127.0f / clipped;

  int rsum = 0;
#pragma unroll
  for (int p = 0; p < 4; ++p) {
    const int w = t + 256 * p;     // output word index 0..1023
    const int b = w >> 5, j = w & 31;
    const int base = b * 128 + j;  // source k for s=0
    const int q0 = quant1(row[base], qs);
    const int q1 = quant1(row[base + 32], qs);
    const int q2 = quant1(row[base + 64], qs);
    const int q3 = quant1(row[base + 96], qs);
    rsum += q0 + q1 + q2 + q3;
    xq[(size_t)n * KW + w] = (unsigned int)(q0 & 255) | ((unsigned int)(q1 & 255) << 8) |
                             ((unsigned int)(q2 & 255) << 16) | ((unsigned int)(q3 & 255) << 24);
  }
#pragma unroll
  for (int off = 32; off; off >>= 1) rsum += __shfl_xor(rsum, off, 64);
  if (lane == 0) redi[wave] = rsum;
  __syncthreads();
  if (t == 0)
    scales[n] = make_float2(clipped * (1.0f / 127.0f),
                            (float)(redi[0] + redi[1] + redi[2] + redi[3]));
}

// Pre-unpack all weights: packed int32 words -> int8 codes (0..3), k-permuted.
__global__ __launch_bounds__(256) void unpack_kernel(const i32x4* __restrict__ in,
                                                     u32x4* __restrict__ outp, int n4) {
  int idx = blockIdx.x * 256 + threadIdx.x;
  const int stride = gridDim.x * 256;
  for (; idx < n4; idx += stride) {
    i32x4 v = in[idx];
    u32x4 u = {unp((unsigned int)v[0]), unp((unsigned int)v[1]),
               unp((unsigned int)v[2]), unp((unsigned int)v[3])};
    outp[idx] = u;
  }
}

// 256x256 tile, BK=128 B, 8 waves (2 row-halves x 4 col-quarters), double-buffered
// LDS, 4-phase-per-K-tile interleave with counted vmcnt (T3+T4), setprio (T5),
// XOR chunk swizzle (round-1 PMC-verified conflict-free), XCD block swizzle (T1).
template <bool PRE>
__global__ __launch_bounds__(512) void bitgemm256(const unsigned char* __restrict__ xq,
                                                  const unsigned char* __restrict__ wu,
                                                  const int* __restrict__ wp,
                                                  const float2* __restrict__ scales,
                                                  const float* __restrict__ wsp,
                                                  float* __restrict__ out) {
  __shared__ __align__(16) unsigned char lds[131072];
  unsigned char* AsB = lds;          // [2][256][128]
  unsigned char* BsB = lds + 65536;  // [2][256][128]

  const int tid = threadIdx.x;
  const int l = tid & 63;
  const int w = tid >> 6;  // 0..7
  const int wm = w >> 2;   // row half 0..1
  const int wn = w & 3;    // col quarter 0..3

  // XCD swizzle: 768 blocks (%8==0 -> bijective), bm-major within each XCD
  const int cpx = gridDim.x >> 3;
  const int swz = (blockIdx.x & 7) * cpx + (blockIdx.x >> 3);
  const int bn = swz & (GN - 1);  // token tile
  const int bm = swz >> 4;        // weight tile

  // staging: thread -> (row in 64-group, 16B chunk), source pre-swizzled
  const int srow = tid >> 3;
  const int schunk = (tid & 7) ^ (srow & 7);
  const size_t soff = (size_t)srow * K_DIM + (schunk << 4);
  const unsigned char* aSrc = xq + (size_t)(bn * BM) * K_DIM + soff;
  const unsigned char* bSrc = wu + (size_t)(bm * BN) * K_DIM + soff;
  const int ldsDst = tid * 16;

  // !PRE fallback: inline unpack of packed words
  const int prow = tid >> 1, phalf = tid & 1;
  const int* pSrc = wp + (size_t)(bm * BN + prow) * KW + phalf * 16;
  const int pchunkbase = phalf * 4;
  const int pswz = prow & 7;
  const int pdst = prow * 128;

  // fragment read byte-offsets; ks=1 toggles bit 6 (chunk+4 pre-swizzle)
  int aoff[8], boff[4];
#pragma unroll
  for (int i = 0; i < 8; ++i) {
    const int r = wm * 128 + i * 16 + (l & 15);
    aoff[i] = r * 128 + (((l >> 4) ^ (r & 7)) << 4);
  }
#pragma unroll
  for (int j = 0; j < 4; ++j) {
    const int r = wn * 64 + j * 16 + (l & 15);
    boff[j] = r * 128 + (((l >> 4) ^ (r & 7)) << 4);
  }

  i32x4 acc[8][4];
#pragma unroll
  for (int i = 0; i < 8; ++i)
#pragma unroll
    for (int j = 0; j < 4; ++j) acc[i][j] = (i32x4){0, 0, 0, 0};

  auto stageAll = [&](int buf, int kb) {
    const int koff = kb * 128;
    unsigned char* ad = AsB + buf * 32768 + ldsDst;
    const unsigned char* as_ = aSrc + koff;
#pragma unroll
    for (int q = 0; q < 4; ++q)
      __builtin_amdgcn_global_load_lds(
          (const __attribute__((address_space(1))) void*)(as_ + (size_t)q * 64 * K_DIM),
          (__attribute__((address_space(3))) void*)(ad + q * 8192), 16, 0, 0);
    if (PRE) {
      unsigned char* bd = BsB + buf * 32768 + ldsDst;
      const unsigned char* bs_ = bSrc + koff;
#pragma unroll
      for (int q = 0; q < 4; ++q)
        __builtin_amdgcn_global_load_lds(
            (const __attribute__((address_space(1))) void*)(bs_ + (size_t)q * 64 * K_DIM),
            (__attribute__((address_space(3))) void*)(bd + q * 8192), 16, 0, 0);
    } else {
      const int* ps = pSrc + kb * 32;
      unsigned char* bd = BsB + buf * 32768 + pdst;
#pragma unroll
      for (int q = 0; q < 4; ++q) {
        i32x4 v = *(const i32x4*)(ps + q * 4);
        u32x4 u = {unp((unsigned int)v[0]), unp((unsigned int)v[1]),
                   unp((unsigned int)v[2]), unp((unsigned int)v[3])};
        *(u32x4*)(bd + (((pchunkbase + q) ^ pswz) << 4)) = u;
      }
    }
  };

  i32x4 af[4], bf[4];
  auto rdA = [&](const unsigned char* Ab, int ih, int k6) {
#pragma unroll
    for (int i = 0; i < 4; ++i) af[i] = *(const i32x4*)(Ab + (aoff[ih * 4 + i] ^ k6));
  };
  auto rdB = [&](const unsigned char* Bb, int k6) {
#pragma unroll
    for (int j = 0; j < 4; ++j) bf[j] = *(const i32x4*)(Bb + (boff[j] ^ k6));
  };
  auto mfma16 = [&](int ih) {
    __builtin_amdgcn_s_setprio(1);
#pragma unroll
    for (int i = 0; i < 4; ++i)
#pragma unroll
      for (int j = 0; j < 4; ++j)
        acc[ih * 4 + i][j] =
            __builtin_amdgcn_mfma_i32_16x16x64_i8(af[i], bf[j], acc[ih * 4 + i][j], 0, 0, 0);
    __builtin_amdgcn_s_setprio(0);
  };

  stageAll(0, 0);
  for (int kb = 0; kb < NT_K; ++kb) {
    const int cur = kb & 1;
    const unsigned char* Ab = AsB + cur * 32768;
    const unsigned char* Bb = BsB + cur * 32768;

    // ---- phase 0: prefetch next tile, counted wait, validate, quadrant (ks0,ih0) ----
    if (kb + 1 < NT_K) {
      stageAll(cur ^ 1, kb + 1);
      if (PRE) {
        asm volatile("s_waitcnt vmcnt(8)" ::: "memory");  // keep next tile's 8 in flight
      } else {
        asm volatile("s_waitcnt vmcnt(4)" ::: "memory");  // next tile's 4 A-loads in flight
        asm volatile("s_waitcnt lgkmcnt(0)" ::: "memory");  // B ds_writes visible
      }
    } else {
      asm volatile("s_waitcnt vmcnt(0)" ::: "memory");
      if (!PRE) asm volatile("s_waitcnt lgkmcnt(0)" ::: "memory");
    }
    __builtin_amdgcn_s_barrier();
    rdA(Ab, 0, 0);
    rdB(Bb, 0);
    mfma16(0);
    __builtin_amdgcn_s_barrier();
    // ---- phase 1: (ks0, ih1) — reuse bf ----
    rdA(Ab, 1, 0);
    mfma16(1);
    __builtin_amdgcn_s_barrier();
    // ---- phase 2: (ks1, ih0) ----
    rdA(Ab, 0, 64);
    rdB(Bb, 64);
    mfma16(0);
    __builtin_amdgcn_s_barrier();
    // ---- phase 3: (ks1, ih1) — reuse bf ----
    rdA(Ab, 1, 64);
    mfma16(1);
    __builtin_amdgcn_s_barrier();
  }

  // epilogue: out = (dot_codes - rowsum) * weight_scale * act_scale
  const float wsc = wsp[0];
#pragma unroll
  for (int i = 0; i < 8; ++i) {
#pragma unroll
    for (int r = 0; r < 4; ++r) {
      const int n = bn * BM + wm * 128 + i * 16 + ((l >> 4) << 2) + r;
      const float2 sc = scales[n];
      const float f = wsc * sc.x;
      float* orow = out + (size_t)n * M_DIM + bm * BN + wn * 64 + (l & 15);
#pragma unroll
      for (int j = 0; j < 4; ++j) orow[j * 16] = ((float)acc[i][j][r] - sc.y) * f;
    }
  }
}

extern "C" void kernel_launch(void* const* d_in, const int* in_sizes, int n_in,
                              void* d_out, int out_size, void* d_ws, size_t ws_size,
                              hipStream_t stream) {
  const float* x = (const float*)d_in[0];
  const int* wp = (const int*)d_in[1];
  const float* wsp = (const float*)d_in[2];
  float* out = (float*)d_out;
  const int N = in_sizes[0] / K_DIM;  // 4096 tokens

  float2* scales = (float2*)d_ws;                           // N * 8 B
  unsigned int* xq = (unsigned int*)((char*)d_ws + 32768);  // N * KW words
  const size_t xq_bytes = (size_t)N * KW * 4;
  unsigned char* wu = (unsigned char*)d_ws + 32768 + xq_bytes;  // M*K codes
  const size_t need = 32768 + xq_bytes + (size_t)M_DIM * K_DIM;

  quant_kernel<<<N, 256, 0, stream>>>(x, xq, scales);
  const int grid = (N / BM) * GM;  // 16 * 48 = 768
  if (ws_size >= need) {
    unpack_kernel<<<2048, 256, 0, stream>>>((const i32x4*)wp, (u32x4*)wu, M_DIM * KW / 4);
    bitgemm256<true><<<grid, 512, 0, stream>>>((const unsigned char*)xq, wu, wp, scales, wsp, out);
  } else {
    bitgemm256<false><<<grid, 512, 0, stream>>>((const unsigned char*)xq, nullptr, wp, scales, wsp,
                                                out);
  }
}

// Round 4
// 236.497 us; speedup vs baseline: 1.0207x; 1.0207x over previous
//
#include <hip/hip_runtime.h>

#define K_DIM 4096
#define M_DIM 12288
#define KW (K_DIM / 4)      // packed int32 words per weight row = 1024
#define NT_K (K_DIM / 128)  // 32 K-tiles of 128 elements (=128 bytes int8)
#define BM 256              // token rows per block tile
#define BN 256              // weight rows per block tile
#define GN 16               // 4096/256 token tiles
#define GM 48               // 12288/256 weight tiles

typedef __attribute__((ext_vector_type(4))) int i32x4;
typedef __attribute__((ext_vector_type(4))) unsigned int u32x4;

__device__ __forceinline__ int quant1(float v, float qs) {
  float r = rintf(v * qs);  // round half-to-even, matches jnp.round
  r = fminf(127.f, fmaxf(-128.f, r));
  return (int)r;
}

// unpack one packed byte into 4 code bytes (0..3) at permuted positions
__device__ __forceinline__ unsigned int unp(unsigned int uv) {
  return ((uv >> 6) | (uv << 4) | (uv << 14) | (uv << 24)) & 0x03030303u;
}

// One block per token row: absmax -> int8 quantize (k-permuted pack) + rowsum.
__global__ __launch_bounds__(256) void quant_kernel(const float* __restrict__ x,
                                                    unsigned int* __restrict__ xq,
                                                    float2* __restrict__ scales) {
  const int n = blockIdx.x;
  const int t = threadIdx.x;
  const float* __restrict__ row = x + (size_t)n * K_DIM;
  const float4* __restrict__ row4 = (const float4*)row;

  float am = 0.f;
#pragma unroll
  for (int p = 0; p < 4; ++p) {
    float4 v = row4[t + 256 * p];
    am = fmaxf(am, fmaxf(fmaxf(fabsf(v.x), fabsf(v.y)), fmaxf(fabsf(v.z), fabsf(v.w))));
  }
#pragma unroll
  for (int off = 32; off; off >>= 1) am = fmaxf(am, __shfl_xor(am, off, 64));
  __shared__ float redf[4];
  __shared__ int redi[4];
  const int wave = t >> 6, lane = t & 63;
  if (lane == 0) redf[wave] = am;
  __syncthreads();
  am = fmaxf(fmaxf(redf[0], redf[1]), fmaxf(redf[2], redf[3]));
  const float clipped = fmaxf(am, 1e-5f);
  const float qs = 127.0f / clipped;

  int rsum = 0;
#pragma unroll
  for (int p = 0; p < 4; ++p) {
    const int w = t + 256 * p;     // output word index 0..1023
    const int b = w >> 5, j = w & 31;
    const int base = b * 128 + j;  // source k for s=0
    const int q0 = quant1(row[base], qs);
    const int q1 = quant1(row[base + 32], qs);
    const int q2 = quant1(row[base + 64], qs);
    const int q3 = quant1(row[base + 96], qs);
    rsum += q0 + q1 + q2 + q3;
    xq[(size_t)n * KW + w] = (unsigned int)(q0 & 255) | ((unsigned int)(q1 & 255) << 8) |
                             ((unsigned int)(q2 & 255) << 16) | ((unsigned int)(q3 & 255) << 24);
  }
#pragma unroll
  for (int off = 32; off; off >>= 1) rsum += __shfl_xor(rsum, off, 64);
  if (lane == 0) redi[wave] = rsum;
  __syncthreads();
  if (t == 0)
    scales[n] = make_float2(clipped * (1.0f / 127.0f),
                            (float)(redi[0] + redi[1] + redi[2] + redi[3]));
}

// Pre-unpack all weights: packed int32 words -> int8 codes (0..3), k-permuted.
__global__ __launch_bounds__(256) void unpack_kernel(const i32x4* __restrict__ in,
                                                     u32x4* __restrict__ outp, int n4) {
  int idx = blockIdx.x * 256 + threadIdx.x;
  const int stride = gridDim.x * 256;
  for (; idx < n4; idx += stride) {
    i32x4 v = in[idx];
    u32x4 u = {unp((unsigned int)v[0]), unp((unsigned int)v[1]),
               unp((unsigned int)v[2]), unp((unsigned int)v[3])};
    outp[idx] = u;
  }
}

// fragment-read / mfma macros: static indices only (rule #20)
#define RD_A(dst, ih, k6, Ab)                                                      \
  {                                                                                \
    _Pragma("unroll") for (int i_ = 0; i_ < 4; ++i_) dst[i_] =                     \
        *(const i32x4*)((Ab) + (aoff[(ih) * 4 + i_] ^ (k6)));                      \
  }
#define RD_B(dst, k6, Bb)                                                          \
  {                                                                                \
    _Pragma("unroll") for (int j_ = 0; j_ < 4; ++j_) dst[j_] =                     \
        *(const i32x4*)((Bb) + (boff[j_] ^ (k6)));                                 \
  }
#define MF16(aA, bB, ih)                                                           \
  {                                                                                \
    __builtin_amdgcn_s_setprio(1);                                                 \
    _Pragma("unroll") for (int i_ = 0; i_ < 4; ++i_)                               \
        _Pragma("unroll") for (int j_ = 0; j_ < 4; ++j_) acc[(ih) * 4 + i_][j_] =  \
            __builtin_amdgcn_mfma_i32_16x16x64_i8(aA[i_], bB[j_],                  \
                                                  acc[(ih) * 4 + i_][j_], 0, 0, 0);\
    __builtin_amdgcn_s_setprio(0);                                                 \
  }

// 256x256 tile, BK=128 B, 8 waves (2 row-halves x 4 col-quarters), double-buffered
// LDS, 4-phase K-tile with ONE-PHASE-AHEAD fragment pre-reads (reads in flight
// under prior phase's MFMAs), counted vmcnt staging, setprio, XOR chunk swizzle
// (round-1 PMC-verified conflict-free), XCD block swizzle.
template <bool PRE>
__global__ __launch_bounds__(512, 2) void bitgemm256(const unsigned char* __restrict__ xq,
                                                     const unsigned char* __restrict__ wu,
                                                     const int* __restrict__ wp,
                                                     const float2* __restrict__ scales,
                                                     const float* __restrict__ wsp,
                                                     float* __restrict__ out) {
  __shared__ __align__(16) unsigned char lds[131072];
  unsigned char* AsB = lds;          // [2][256][128]
  unsigned char* BsB = lds + 65536;  // [2][256][128]

  const int tid = threadIdx.x;
  const int l = tid & 63;
  const int w = tid >> 6;  // 0..7
  const int wm = w >> 2;   // row half 0..1
  const int wn = w & 3;    // col quarter 0..3

  // XCD swizzle: 768 blocks (%8==0 -> bijective), bm-major within each XCD
  const int cpx = gridDim.x >> 3;
  const int swz = (blockIdx.x & 7) * cpx + (blockIdx.x >> 3);
  const int bn = swz & (GN - 1);  // token tile
  const int bm = swz >> 4;        // weight tile

  // staging: thread -> (row in 64-group, 16B chunk), source pre-swizzled
  const int srow = tid >> 3;
  const int schunk = (tid & 7) ^ (srow & 7);
  const size_t soff = (size_t)srow * K_DIM + (schunk << 4);
  const unsigned char* aSrc = xq + (size_t)(bn * BM) * K_DIM + soff;
  const unsigned char* bSrc = wu + (size_t)(bm * BN) * K_DIM + soff;
  const int ldsDst = tid * 16;

  // !PRE fallback: inline unpack of packed words
  const int prow = tid >> 1, phalf = tid & 1;
  const int* pSrc = wp + (size_t)(bm * BN + prow) * KW + phalf * 16;
  const int pchunkbase = phalf * 4;
  const int pswz = prow & 7;
  const int pdst = prow * 128;

  // fragment read byte-offsets; ks=1 toggles bit 6 (chunk+4 pre-swizzle)
  int aoff[8], boff[4];
#pragma unroll
  for (int i = 0; i < 8; ++i) {
    const int r = wm * 128 + i * 16 + (l & 15);
    aoff[i] = r * 128 + (((l >> 4) ^ (r & 7)) << 4);
  }
#pragma unroll
  for (int j = 0; j < 4; ++j) {
    const int r = wn * 64 + j * 16 + (l & 15);
    boff[j] = r * 128 + (((l >> 4) ^ (r & 7)) << 4);
  }

  i32x4 acc[8][4];
#pragma unroll
  for (int i = 0; i < 8; ++i)
#pragma unroll
    for (int j = 0; j < 4; ++j) acc[i][j] = (i32x4){0, 0, 0, 0};

  auto stageAll = [&](int buf, int kb) {
    const int koff = kb * 128;
    unsigned char* ad = AsB + buf * 32768 + ldsDst;
    const unsigned char* as_ = aSrc + koff;
#pragma unroll
    for (int q = 0; q < 4; ++q)
      __builtin_amdgcn_global_load_lds(
          (const __attribute__((address_space(1))) void*)(as_ + (size_t)q * 64 * K_DIM),
          (__attribute__((address_space(3))) void*)(ad + q * 8192), 16, 0, 0);
    if (PRE) {
      unsigned char* bd = BsB + buf * 32768 + ldsDst;
      const unsigned char* bs_ = bSrc + koff;
#pragma unroll
      for (int q = 0; q < 4; ++q)
        __builtin_amdgcn_global_load_lds(
            (const __attribute__((address_space(1))) void*)(bs_ + (size_t)q * 64 * K_DIM),
            (__attribute__((address_space(3))) void*)(bd + q * 8192), 16, 0, 0);
    } else {
      const int* ps = pSrc + kb * 32;
      unsigned char* bd = BsB + buf * 32768 + pdst;
#pragma unroll
      for (int q = 0; q < 4; ++q) {
        i32x4 v = *(const i32x4*)(ps + q * 4);
        u32x4 u = {unp((unsigned int)v[0]), unp((unsigned int)v[1]),
                   unp((unsigned int)v[2]), unp((unsigned int)v[3])};
        *(u32x4*)(bd + (((pchunkbase + q) ^ pswz) << 4)) = u;
      }
    }
  };

  i32x4 afX[4], afY[4], bfX[4], bfY[4];

  stageAll(0, 0);
  for (int kb = 0; kb < NT_K; ++kb) {
    const int cur = kb & 1;
    const unsigned char* Ab = AsB + cur * 32768;
    const unsigned char* Bb = BsB + cur * 32768;

    if (kb + 1 < NT_K) {
      stageAll(cur ^ 1, kb + 1);
      if (PRE) {
        asm volatile("s_waitcnt vmcnt(8)" ::: "memory");  // next tile's 8 stay in flight
      } else {
        asm volatile("s_waitcnt vmcnt(4)" ::: "memory");
        asm volatile("s_waitcnt lgkmcnt(0)" ::: "memory");
      }
    } else {
      asm volatile("s_waitcnt vmcnt(0)" ::: "memory");
      if (!PRE) asm volatile("s_waitcnt lgkmcnt(0)" ::: "memory");
    }
    __builtin_amdgcn_s_barrier();  // buf[cur] validated for all waves

    // P0: Q0 reads + Q1 pre-read, then MFMA Q0 (Q1 reads in flight underneath)
    RD_A(afX, 0, 0, Ab);
    RD_B(bfX, 0, Bb);
    RD_A(afY, 1, 0, Ab);
    MF16(afX, bfX, 0);
    __builtin_amdgcn_s_barrier();
    // P1: Q2 pre-read (A' + B'), then MFMA Q1
    RD_A(afX, 0, 64, Ab);
    RD_B(bfY, 64, Bb);
    MF16(afY, bfX, 1);
    __builtin_amdgcn_s_barrier();
    // P2: Q3 pre-read, then MFMA Q2
    RD_A(afY, 1, 64, Ab);
    MF16(afX, bfY, 0);
    __builtin_amdgcn_s_barrier();
    // P3: pure MFMA Q3
    MF16(afY, bfY, 1);
    __builtin_amdgcn_s_barrier();
  }

  // epilogue: out = (dot_codes - rowsum) * weight_scale * act_scale
  const float wsc = wsp[0];
#pragma unroll
  for (int i = 0; i < 8; ++i) {
#pragma unroll
    for (int r = 0; r < 4; ++r) {
      const int n = bn * BM + wm * 128 + i * 16 + ((l >> 4) << 2) + r;
      const float2 sc = scales[n];
      const float f = wsc * sc.x;
      float* orow = out + (size_t)n * M_DIM + bm * BN + wn * 64 + (l & 15);
#pragma unroll
      for (int j = 0; j < 4; ++j) orow[j * 16] = ((float)acc[i][j][r] - sc.y) * f;
    }
  }
}

extern "C" void kernel_launch(void* const* d_in, const int* in_sizes, int n_in,
                              void* d_out, int out_size, void* d_ws, size_t ws_size,
                              hipStream_t stream) {
  const float* x = (const float*)d_in[0];
  const int* wp = (const int*)d_in[1];
  const float* wsp = (const float*)d_in[2];
  float* out = (float*)d_out;
  const int N = in_sizes[0] / K_DIM;  // 4096 tokens

  float2* scales = (float2*)d_ws;                           // N * 8 B
  unsigned int* xq = (unsigned int*)((char*)d_ws + 32768);  // N * KW words
  const size_t xq_bytes = (size_t)N * KW * 4;
  unsigned char* wu = (unsigned char*)d_ws + 32768 + xq_bytes;  // M*K codes
  const size_t need = 32768 + xq_bytes + (size_t)M_DIM * K_DIM;

  quant_kernel<<<N, 256, 0, stream>>>(x, xq, scales);
  const int grid = (N / BM) * GM;  // 16 * 48 = 768
  if (ws_size >= need) {
    unpack_kernel<<<2048, 256, 0, stream>>>((const i32x4*)wp, (u32x4*)wu, M_DIM * KW / 4);
    bitgemm256<true><<<grid, 512, 0, stream>>>((const unsigned char*)xq, wu, wp, scales, wsp, out);
  } else {
    bitgemm256<false><<<grid, 512, 0, stream>>>((const unsigned char*)xq, nullptr, wp, scales, wsp,
                                                out);
  }
}